// Round 4
// baseline (641.244 us; speedup 1.0000x reference)
//
#include <hip/hip_runtime.h>
#include <hip/hip_bf16.h>

typedef __bf16 bf16x8 __attribute__((ext_vector_type(8)));
typedef float  f32x4  __attribute__((ext_vector_type(4)));

#define RSX 136            // x_t row stride (elems): 64 rows x 128 cols (+8 pad); rows 16B-aligned
#define RSH 264            // h_t row stride (elems): 64 rows x 256 cols (+8 pad)
#define LDS_XT 0
#define LDS_HT (64 * RSX)

__device__ __forceinline__ ushort f2bf(float f) {
    union { float f; uint i; } c; c.f = f;
    uint u = c.i;
    u = (u + 0x7fff + ((u >> 16) & 1)) >> 16;   // RTNE
    return (ushort)u;
}
// Clamped: exp arg bounded => no inf/NaN possible in the elementwise path.
__device__ __forceinline__ float sigmoidf_(float x) {
    x = fminf(fmaxf(x, -30.0f), 30.0f);
    return 1.0f / (1.0f + expf(-x));
}
__device__ __forceinline__ float tanhf_(float x) {
    x = fminf(fmaxf(x, -15.0f), 15.0f);
    const float e = expf(-2.0f * x);
    return (1.0f - e) / (1.0f + e);
}

// ---------------------------------------------------------------------------
// Prep: fp32 weights -> bf16 B^T GEMM layout Wt[r][kt], kt-contiguous.
//   row r: gate = (r>>4)&3 ; ch = ((r>>6)<<4) | (r&15)
//   col kt: kt<1152: x taps, seg=kt>>7, ic=kt&127 ; else h taps, seg=(kt-1152)>>8, ic=&255
// ---------------------------------------------------------------------------
__global__ void prep_wt(const float* __restrict__ wii, const float* __restrict__ wif,
                        const float* __restrict__ wig, const float* __restrict__ wio,
                        const float* __restrict__ whi, const float* __restrict__ whf,
                        const float* __restrict__ whg, const float* __restrict__ who,
                        ushort* __restrict__ Wt) {
    const int r  = blockIdx.y;
    const int kt = blockIdx.x * 128 + threadIdx.x;
    const int gate = (r >> 4) & 3;
    const int ch   = ((r >> 6) << 4) | (r & 15);
    const float* wi = (gate == 0) ? wii : (gate == 1) ? wif : (gate == 2) ? wig : wio;
    const float* wh = (gate == 0) ? whi : (gate == 1) ? whf : (gate == 2) ? whg : who;
    float v;
    if (kt < 1152) {
        const int seg = kt >> 7, ic = kt & 127;
        v = wi[(ch * 128 + ic) * 9 + seg];
    } else {
        const int k2 = kt - 1152;
        const int seg = k2 >> 8, ic = k2 & 255;
        v = wh[(ch * 256 + ic) * 9 + seg];
    }
    Wt[r * 3456 + kt] = f2bf(v);
}

__global__ void prep_bias(const float* __restrict__ bii, const float* __restrict__ bif,
                          const float* __restrict__ big, const float* __restrict__ bio,
                          const float* __restrict__ bhi, const float* __restrict__ bhf,
                          const float* __restrict__ bhg, const float* __restrict__ bho,
                          float* __restrict__ btot) {
    const int g = blockIdx.x, ch = threadIdx.x;
    const float* bi = (g == 0) ? bii : (g == 1) ? bif : (g == 2) ? big : bio;
    const float* bh = (g == 0) ? bhi : (g == 1) ? bhf : (g == 2) ? bhg : bho;
    btot[g * 256 + ch] = bi[ch] + bh[ch];
}

// ---------------------------------------------------------------------------
// Main: one block = one image x 256 oc columns. fp32 in/out, bf16 MFMA core.
//  - stage x (64px x 128ic) and h0 (64 x 256) transposed+bf16 into LDS
//  - single __syncthreads, then barrier-free K loop (A in LDS, B from L2)
//  - reflect-shift = permuted LDS row address
//  - in-lane fused LSTM epilogue (4 gates of one channel in one lane's accs)
// ---------------------------------------------------------------------------
__global__ __launch_bounds__(256, 2)
void convlstm_main(const float* __restrict__ x, const float* __restrict__ hidden,
                   const ushort* __restrict__ Wt, const float* __restrict__ btot,
                   const float* __restrict__ wci, const float* __restrict__ wcf,
                   const float* __restrict__ wco, float* __restrict__ out) {
    __shared__ alignas(16) ushort lds[64 * RSX + 64 * RSH];   // 50 KB

    const int img    = blockIdx.x;
    const int octile = blockIdx.y;
    const int tid    = threadIdx.x;
    const int lane   = tid & 63;
    const int wave   = tid >> 6;
    const int lm     = lane & 15;   // A-row / B-col index
    const int kg     = lane >> 4;   // k-group (quad)

    // ---- stage x: fp32 [ic][p] -> bf16 LDS [p][ic]; lanes along ic => LDS-conflict-free
    {
        const float* xs = x + img * 8192;
        #pragma unroll
        for (int it = 0; it < 4; ++it) {
            const int icp = lane;                // ic pair 0..63
            const int p0  = (it * 4 + wave) * 4; // pixel group
            const float4 f0 = *(const float4*)(xs + (2 * icp    ) * 64 + p0);
            const float4 f1 = *(const float4*)(xs + (2 * icp + 1) * 64 + p0);
            const float a0[4] = {f0.x, f0.y, f0.z, f0.w};
            const float a1[4] = {f1.x, f1.y, f1.z, f1.w};
            #pragma unroll
            for (int j = 0; j < 4; ++j) {
                const uint pk = (uint)f2bf(a0[j]) | ((uint)f2bf(a1[j]) << 16);
                *(uint*)(&lds[LDS_XT + (p0 + j) * RSX + 2 * icp]) = pk;
            }
        }
        const float* hs = hidden + img * 32768;   // h0 = hidden[img][0]
        #pragma unroll
        for (int it = 0; it < 8; ++it) {
            const int icp = (it & 1) * 64 + lane;       // ic pair 0..127
            const int p0  = ((it >> 1) * 4 + wave) * 4; // pixel group
            const float4 f0 = *(const float4*)(hs + (2 * icp    ) * 64 + p0);
            const float4 f1 = *(const float4*)(hs + (2 * icp + 1) * 64 + p0);
            const float a0[4] = {f0.x, f0.y, f0.z, f0.w};
            const float a1[4] = {f1.x, f1.y, f1.z, f1.w};
            #pragma unroll
            for (int j = 0; j < 4; ++j) {
                const uint pk = (uint)f2bf(a0[j]) | ((uint)f2bf(a1[j]) << 16);
                *(uint*)(&lds[LDS_HT + (p0 + j) * RSH + 2 * icp]) = pk;
            }
        }
    }
    __syncthreads();

    f32x4 acc[4][4];   // [m_sub][gate]
    #pragma unroll
    for (int ms = 0; ms < 4; ++ms)
        #pragma unroll
        for (int ns = 0; ns < 4; ++ns)
            #pragma unroll
            for (int r = 0; r < 4; ++r) acc[ms][ns][r] = 0.0f;

    const int ocbase = octile * 256 + wave * 64;
    const ushort* Brow = Wt + (ocbase + lm) * 3456 + kg * 8;

    // ---- x taps: 9 segments x K=128
    #pragma unroll 1
    for (int seg = 0; seg < 9; ++seg) {
        const int dy = seg / 3 - 1, dx = seg % 3 - 1;
        int aoff[4];
        #pragma unroll
        for (int ms = 0; ms < 4; ++ms) {
            const int pm = ms * 16 + lm;
            const int yy = pm >> 3, xx = pm & 7;
            int sy = yy + dy; sy = (sy < 0) ? 1 : ((sy > 7) ? 6 : sy);
            int sx = xx + dx; sx = (sx < 0) ? 1 : ((sx > 7) ? 6 : sx);
            aoff[ms] = LDS_XT + (sy * 8 + sx) * RSX + kg * 8;
        }
        #pragma unroll
        for (int ic0 = 0; ic0 < 128; ic0 += 32) {
            const int kt = seg * 128 + ic0;
            bf16x8 a[4], b[4];
            #pragma unroll
            for (int ms = 0; ms < 4; ++ms) a[ms] = *(const bf16x8*)(&lds[aoff[ms] + ic0]);
            #pragma unroll
            for (int ns = 0; ns < 4; ++ns) b[ns] = *(const bf16x8*)(Brow + ns * 16 * 3456 + kt);
            #pragma unroll
            for (int ms = 0; ms < 4; ++ms)
                #pragma unroll
                for (int ns = 0; ns < 4; ++ns)
                    acc[ms][ns] = __builtin_amdgcn_mfma_f32_16x16x32_bf16(a[ms], b[ns], acc[ms][ns], 0, 0, 0);
        }
    }

    // ---- h taps: 9 segments x K=256
    #pragma unroll 1
    for (int seg = 0; seg < 9; ++seg) {
        const int dy = seg / 3 - 1, dx = seg % 3 - 1;
        int aoff[4];
        #pragma unroll
        for (int ms = 0; ms < 4; ++ms) {
            const int pm = ms * 16 + lm;
            const int yy = pm >> 3, xx = pm & 7;
            int sy = yy + dy; sy = (sy < 0) ? 1 : ((sy > 7) ? 6 : sy);
            int sx = xx + dx; sx = (sx < 0) ? 1 : ((sx > 7) ? 6 : sx);
            aoff[ms] = LDS_HT + (sy * 8 + sx) * RSH + kg * 8;
        }
        #pragma unroll
        for (int ic0 = 0; ic0 < 256; ic0 += 32) {
            const int kt = 1152 + seg * 256 + ic0;
            bf16x8 a[4], b[4];
            #pragma unroll
            for (int ms = 0; ms < 4; ++ms) a[ms] = *(const bf16x8*)(&lds[aoff[ms] + ic0]);
            #pragma unroll
            for (int ns = 0; ns < 4; ++ns) b[ns] = *(const bf16x8*)(Brow + ns * 16 * 3456 + kt);
            #pragma unroll
            for (int ms = 0; ms < 4; ++ms)
                #pragma unroll
                for (int ns = 0; ns < 4; ++ns)
                    acc[ms][ns] = __builtin_amdgcn_mfma_f32_16x16x32_bf16(a[ms], b[ns], acc[ms][ns], 0, 0, 0);
        }
    }

    // ---- fused LSTM epilogue (in-lane: n_sub == gate), fp32 I/O
    const int ch   = (octile * 4 + wave) * 16 + lm;
    const int quad = lane >> 4;

    const float* h0p = hidden + img * 32768 + ch * 64;
    const float* c0p = h0p + 16384;
    const float* wip = wci + ch * 64;
    const float* wfp = wcf + ch * 64;
    const float* wop = wco + ch * 64;
    const float bi_ = btot[      ch];
    const float bf_ = btot[256 + ch];
    const float bg_ = btot[512 + ch];
    const float bo_ = btot[768 + ch];

    float* o_out = out + img * 16384 + ch * 64;
    float* h_out = out + 8388608 + img * 32768 + ch * 64;   // hidden_out[img][0]
    float* c_out = h_out + 16384;                           // hidden_out[img][1]

    #pragma unroll
    for (int ms = 0; ms < 4; ++ms) {
        const int P0 = ms * 16 + quad * 4;   // 4 consecutive pixels per lane (C/D rows)
        union { float4 v; float f[4]; } c0u, h0u, wiu, wfu, wou, ov4, hv4, cv4;
        c0u.v = *(const float4*)(c0p + P0);
        h0u.v = *(const float4*)(h0p + P0);
        wiu.v = *(const float4*)(wip + P0);
        wfu.v = *(const float4*)(wfp + P0);
        wou.v = *(const float4*)(wop + P0);
        #pragma unroll
        for (int r = 0; r < 4; ++r) {
            const float c0v = c0u.f[r];
            const float h0v = h0u.f[r];
            const float gi = acc[ms][0][r] + bi_;
            const float gf = acc[ms][1][r] + bf_;
            const float gg = acc[ms][2][r] + bg_;
            const float go = acc[ms][3][r] + bo_;
            const float iv = sigmoidf_(gi + c0v * wiu.f[r]);
            const float fv = sigmoidf_(gf + c0v * wfu.f[r]);
            const float gv = tanhf_(gg);
            const float ct = c0v + fv * c0v + iv * gv;
            const float ov = sigmoidf_(go + ct * wou.f[r]);
            const float ht = h0v + ov * tanhf_(ct);
            ov4.f[r] = ov;
            hv4.f[r] = ht;
            cv4.f[r] = ct;
        }
        *(float4*)(o_out + P0) = ov4.v;
        *(float4*)(h_out + P0) = hv4.v;
        *(float4*)(c_out + P0) = cv4.v;
    }
}

extern "C" void kernel_launch(void* const* d_in, const int* in_sizes, int n_in,
                              void* d_out, int out_size, void* d_ws, size_t ws_size,
                              hipStream_t stream) {
    const float* x      = (const float*)d_in[0];
    const float* hidden = (const float*)d_in[1];
    const float* wii = (const float*)d_in[2];  const float* bii = (const float*)d_in[3];
    const float* wif = (const float*)d_in[4];  const float* bif = (const float*)d_in[5];
    const float* wig = (const float*)d_in[6];  const float* big = (const float*)d_in[7];
    const float* wio = (const float*)d_in[8];  const float* bio = (const float*)d_in[9];
    const float* whi = (const float*)d_in[10]; const float* bhi = (const float*)d_in[11];
    const float* whf = (const float*)d_in[12]; const float* bhf = (const float*)d_in[13];
    const float* whg = (const float*)d_in[14]; const float* bhg = (const float*)d_in[15];
    const float* who = (const float*)d_in[16]; const float* bho = (const float*)d_in[17];
    const float* wci = (const float*)d_in[18];
    const float* wcf = (const float*)d_in[19];
    const float* wco = (const float*)d_in[20];

    ushort* Wt  = (ushort*)d_ws;                               // 1024*3456 bf16 = 6.75 MiB
    float* btot = (float*)((char*)d_ws + (size_t)1024 * 3456 * 2);

    prep_wt<<<dim3(27, 1024), 128, 0, stream>>>(wii, wif, wig, wio, whi, whf, whg, who, Wt);
    prep_bias<<<dim3(4), 256, 0, stream>>>(bii, bif, big, bio, bhi, bhf, bhg, bho, btot);
    convlstm_main<<<dim3(512, 4), 256, 0, stream>>>(x, hidden, Wt, btot, wci, wcf, wco,
                                                    (float*)d_out);
}

// Round 5
// 623.110 us; speedup vs baseline: 1.0291x; 1.0291x over previous
//
#include <hip/hip_runtime.h>
#include <hip/hip_bf16.h>

typedef __bf16 bf16x8 __attribute__((ext_vector_type(8)));
typedef float  f32x4  __attribute__((ext_vector_type(4)));

#define RSX 136            // x_t row stride (elems): 64 rows x 128 cols (+8 pad); rows 16B-aligned
#define RSH 264            // h_t row stride (elems): 64 rows x 256 cols (+8 pad)
#define LDS_XT 0
#define LDS_HT (64 * RSX)

__device__ __forceinline__ ushort f2bf(float f) {
    union { float f; uint i; } c; c.f = f;
    uint u = c.i;
    u = (u + 0x7fff + ((u >> 16) & 1)) >> 16;   // RTNE
    return (ushort)u;
}
// Clamped: exp arg bounded => no inf/NaN possible in the elementwise path.
__device__ __forceinline__ float sigmoidf_(float x) {
    x = fminf(fmaxf(x, -30.0f), 30.0f);
    return 1.0f / (1.0f + expf(-x));
}
__device__ __forceinline__ float tanhf_(float x) {
    x = fminf(fmaxf(x, -15.0f), 15.0f);
    const float e = expf(-2.0f * x);
    return (1.0f - e) / (1.0f + e);
}

// ---------------------------------------------------------------------------
// Prep (coalesced): fp32 weights -> bf16 B^T layout Wt[r][kt].
// One thread per (gate,ch,ic); reads 9 contiguous floats (fully coalesced
// across a warp), writes 9 per-seg coalesced ushort stores.
//   row r = ((ch>>4)<<6) | (gate<<4) | (ch&15)
//   x taps at kt = seg*128 + ic ; h taps at kt = 1152 + seg*256 + ic
// ---------------------------------------------------------------------------
__global__ void prep_wt(const float* __restrict__ wii, const float* __restrict__ wif,
                        const float* __restrict__ wig, const float* __restrict__ wio,
                        const float* __restrict__ whi, const float* __restrict__ whf,
                        const float* __restrict__ whg, const float* __restrict__ who,
                        ushort* __restrict__ Wt) {
    const int idx = blockIdx.x * 256 + threadIdx.x;
    if (idx < 131072) {                       // x weights: 4 gates x 256 ch x 128 ic
        const int g   = idx >> 15;
        const int rem = idx & 32767;
        const int ch  = rem >> 7, ic = rem & 127;
        const float* w = (g == 0) ? wii : (g == 1) ? wif : (g == 2) ? wig : wio;
        const int r = ((ch >> 4) << 6) | (g << 4) | (ch & 15);
        const float* src = w + (size_t)(ch * 128 + ic) * 9;
        ushort* dst = Wt + (size_t)r * 3456;
        #pragma unroll
        for (int s = 0; s < 9; ++s) dst[s * 128 + ic] = f2bf(src[s]);
    } else {                                  // h weights: 4 gates x 256 ch x 256 ic
        const int j   = idx - 131072;
        const int g   = j >> 16;
        const int rem = j & 65535;
        const int ch  = rem >> 8, ic = rem & 255;
        const float* w = (g == 0) ? whi : (g == 1) ? whf : (g == 2) ? whg : who;
        const int r = ((ch >> 4) << 6) | (g << 4) | (ch & 15);
        const float* src = w + (size_t)(ch * 256 + ic) * 9;
        ushort* dst = Wt + (size_t)r * 3456 + 1152;
        #pragma unroll
        for (int s = 0; s < 9; ++s) dst[s * 256 + ic] = f2bf(src[s]);
    }
}

__global__ void prep_bias(const float* __restrict__ bii, const float* __restrict__ bif,
                          const float* __restrict__ big, const float* __restrict__ bio,
                          const float* __restrict__ bhi, const float* __restrict__ bhf,
                          const float* __restrict__ bhg, const float* __restrict__ bho,
                          float* __restrict__ btot) {
    const int g = blockIdx.x, ch = threadIdx.x;
    const float* bi = (g == 0) ? bii : (g == 1) ? bif : (g == 2) ? big : bio;
    const float* bh = (g == 0) ? bhi : (g == 1) ? bhf : (g == 2) ? bhg : bho;
    btot[g * 256 + ch] = bi[ch] + bh[ch];
}

// ---------------------------------------------------------------------------
// Main: one block = one image x 256 oc columns. fp32 in/out, bf16 MFMA core.
//  - grid (octile=4, img=512): linear block id = oct + 4*img -> with the 8-XCD
//    round-robin, each XCD serves ONE octile -> its 1.77 MB Wt slice stays
//    L2-resident for all 512 images (was: 4 slices = 7 MB thrashing to L3).
//  - stage x (64px x 128ic) and h0 (64 x 256) transposed+bf16 into LDS
//  - single __syncthreads, then barrier-free K loop (A in LDS, B from L2)
//  - reflect-shift = permuted LDS row address
//  - in-lane fused LSTM epilogue (4 gates of one channel in one lane's accs)
// ---------------------------------------------------------------------------
__global__ __launch_bounds__(256, 3)
void convlstm_main(const float* __restrict__ x, const float* __restrict__ hidden,
                   const ushort* __restrict__ Wt, const float* __restrict__ btot,
                   const float* __restrict__ wci, const float* __restrict__ wcf,
                   const float* __restrict__ wco, float* __restrict__ out) {
    __shared__ alignas(16) ushort lds[64 * RSX + 64 * RSH];   // 50 KB -> 3 blocks/CU

    const int octile = blockIdx.x;   // fast dim -> XCD-pinned
    const int img    = blockIdx.y;
    const int tid    = threadIdx.x;
    const int lane   = tid & 63;
    const int wave   = tid >> 6;
    const int lm     = lane & 15;   // A-row / B-col index
    const int kg     = lane >> 4;   // k-group (quad)

    // ---- stage x: fp32 [ic][p] -> bf16 LDS [p][ic]; lanes along ic => conflict-free
    {
        const float* xs = x + img * 8192;
        #pragma unroll
        for (int it = 0; it < 4; ++it) {
            const int icp = lane;                // ic pair 0..63
            const int p0  = (it * 4 + wave) * 4; // pixel group
            const float4 f0 = *(const float4*)(xs + (2 * icp    ) * 64 + p0);
            const float4 f1 = *(const float4*)(xs + (2 * icp + 1) * 64 + p0);
            const float a0[4] = {f0.x, f0.y, f0.z, f0.w};
            const float a1[4] = {f1.x, f1.y, f1.z, f1.w};
            #pragma unroll
            for (int j = 0; j < 4; ++j) {
                const uint pk = (uint)f2bf(a0[j]) | ((uint)f2bf(a1[j]) << 16);
                *(uint*)(&lds[LDS_XT + (p0 + j) * RSX + 2 * icp]) = pk;
            }
        }
        const float* hs = hidden + img * 32768;   // h0 = hidden[img][0]
        #pragma unroll
        for (int it = 0; it < 8; ++it) {
            const int icp = (it & 1) * 64 + lane;       // ic pair 0..127
            const int p0  = ((it >> 1) * 4 + wave) * 4; // pixel group
            const float4 f0 = *(const float4*)(hs + (2 * icp    ) * 64 + p0);
            const float4 f1 = *(const float4*)(hs + (2 * icp + 1) * 64 + p0);
            const float a0[4] = {f0.x, f0.y, f0.z, f0.w};
            const float a1[4] = {f1.x, f1.y, f1.z, f1.w};
            #pragma unroll
            for (int j = 0; j < 4; ++j) {
                const uint pk = (uint)f2bf(a0[j]) | ((uint)f2bf(a1[j]) << 16);
                *(uint*)(&lds[LDS_HT + (p0 + j) * RSH + 2 * icp]) = pk;
            }
        }
    }
    __syncthreads();

    f32x4 acc[4][4];   // [m_sub][gate]
    #pragma unroll
    for (int ms = 0; ms < 4; ++ms)
        #pragma unroll
        for (int ns = 0; ns < 4; ++ns)
            #pragma unroll
            for (int r = 0; r < 4; ++r) acc[ms][ns][r] = 0.0f;

    const int ocbase = octile * 256 + wave * 64;
    const ushort* Brow = Wt + (size_t)(ocbase + lm) * 3456 + kg * 8;

    // ---- x taps: 9 segments x K=128
    #pragma unroll 1
    for (int seg = 0; seg < 9; ++seg) {
        const int dy = seg / 3 - 1, dx = seg % 3 - 1;
        int aoff[4];
        #pragma unroll
        for (int ms = 0; ms < 4; ++ms) {
            const int pm = ms * 16 + lm;
            const int yy = pm >> 3, xx = pm & 7;
            int sy = yy + dy; sy = (sy < 0) ? 1 : ((sy > 7) ? 6 : sy);
            int sx = xx + dx; sx = (sx < 0) ? 1 : ((sx > 7) ? 6 : sx);
            aoff[ms] = LDS_XT + (sy * 8 + sx) * RSX + kg * 8;
        }
        #pragma unroll
        for (int ic0 = 0; ic0 < 128; ic0 += 32) {
            const int kt = seg * 128 + ic0;
            bf16x8 a[4], b[4];
            #pragma unroll
            for (int ms = 0; ms < 4; ++ms) a[ms] = *(const bf16x8*)(&lds[aoff[ms] + ic0]);
            #pragma unroll
            for (int ns = 0; ns < 4; ++ns) b[ns] = *(const bf16x8*)(Brow + (size_t)ns * 16 * 3456 + kt);
            #pragma unroll
            for (int ms = 0; ms < 4; ++ms)
                #pragma unroll
                for (int ns = 0; ns < 4; ++ns)
                    acc[ms][ns] = __builtin_amdgcn_mfma_f32_16x16x32_bf16(a[ms], b[ns], acc[ms][ns], 0, 0, 0);
        }
    }

    // ---- h taps: 9 segments x K=256
    #pragma unroll 1
    for (int seg = 0; seg < 9; ++seg) {
        const int dy = seg / 3 - 1, dx = seg % 3 - 1;
        int aoff[4];
        #pragma unroll
        for (int ms = 0; ms < 4; ++ms) {
            const int pm = ms * 16 + lm;
            const int yy = pm >> 3, xx = pm & 7;
            int sy = yy + dy; sy = (sy < 0) ? 1 : ((sy > 7) ? 6 : sy);
            int sx = xx + dx; sx = (sx < 0) ? 1 : ((sx > 7) ? 6 : sx);
            aoff[ms] = LDS_HT + (sy * 8 + sx) * RSH + kg * 8;
        }
        #pragma unroll
        for (int ic0 = 0; ic0 < 256; ic0 += 32) {
            const int kt = 1152 + seg * 256 + ic0;
            bf16x8 a[4], b[4];
            #pragma unroll
            for (int ms = 0; ms < 4; ++ms) a[ms] = *(const bf16x8*)(&lds[aoff[ms] + ic0]);
            #pragma unroll
            for (int ns = 0; ns < 4; ++ns) b[ns] = *(const bf16x8*)(Brow + (size_t)ns * 16 * 3456 + kt);
            #pragma unroll
            for (int ms = 0; ms < 4; ++ms)
                #pragma unroll
                for (int ns = 0; ns < 4; ++ns)
                    acc[ms][ns] = __builtin_amdgcn_mfma_f32_16x16x32_bf16(a[ms], b[ns], acc[ms][ns], 0, 0, 0);
        }
    }

    // ---- fused LSTM epilogue (in-lane: n_sub == gate), fp32 I/O
    const int ch   = (octile * 4 + wave) * 16 + lm;
    const int quad = lane >> 4;

    const float* h0p = hidden + img * 32768 + ch * 64;
    const float* c0p = h0p + 16384;
    const float* wip = wci + ch * 64;
    const float* wfp = wcf + ch * 64;
    const float* wop = wco + ch * 64;
    const float bi_ = btot[      ch];
    const float bf_ = btot[256 + ch];
    const float bg_ = btot[512 + ch];
    const float bo_ = btot[768 + ch];

    float* o_out = out + img * 16384 + ch * 64;
    float* h_out = out + 8388608 + img * 32768 + ch * 64;   // hidden_out[img][0]
    float* c_out = h_out + 16384;                           // hidden_out[img][1]

    #pragma unroll
    for (int ms = 0; ms < 4; ++ms) {
        const int P0 = ms * 16 + quad * 4;   // 4 consecutive pixels per lane (C/D rows)
        union { float4 v; float f[4]; } c0u, h0u, wiu, wfu, wou, ov4, hv4, cv4;
        c0u.v = *(const float4*)(c0p + P0);
        h0u.v = *(const float4*)(h0p + P0);
        wiu.v = *(const float4*)(wip + P0);
        wfu.v = *(const float4*)(wfp + P0);
        wou.v = *(const float4*)(wop + P0);
        #pragma unroll
        for (int r = 0; r < 4; ++r) {
            const float c0v = c0u.f[r];
            const float h0v = h0u.f[r];
            const float gi = acc[ms][0][r] + bi_;
            const float gf = acc[ms][1][r] + bf_;
            const float gg = acc[ms][2][r] + bg_;
            const float go = acc[ms][3][r] + bo_;
            const float iv = sigmoidf_(gi + c0v * wiu.f[r]);
            const float fv = sigmoidf_(gf + c0v * wfu.f[r]);
            const float gv = tanhf_(gg);
            const float ct = c0v + fv * c0v + iv * gv;
            const float ov = sigmoidf_(go + ct * wou.f[r]);
            const float ht = h0v + ov * tanhf_(ct);
            ov4.f[r] = ov;
            hv4.f[r] = ht;
            cv4.f[r] = ct;
        }
        *(float4*)(o_out + P0) = ov4.v;
        *(float4*)(h_out + P0) = hv4.v;
        *(float4*)(c_out + P0) = cv4.v;
    }
}

extern "C" void kernel_launch(void* const* d_in, const int* in_sizes, int n_in,
                              void* d_out, int out_size, void* d_ws, size_t ws_size,
                              hipStream_t stream) {
    const float* x      = (const float*)d_in[0];
    const float* hidden = (const float*)d_in[1];
    const float* wii = (const float*)d_in[2];  const float* bii = (const float*)d_in[3];
    const float* wif = (const float*)d_in[4];  const float* bif = (const float*)d_in[5];
    const float* wig = (const float*)d_in[6];  const float* big = (const float*)d_in[7];
    const float* wio = (const float*)d_in[8];  const float* bio = (const float*)d_in[9];
    const float* whi = (const float*)d_in[10]; const float* bhi = (const float*)d_in[11];
    const float* whf = (const float*)d_in[12]; const float* bhf = (const float*)d_in[13];
    const float* whg = (const float*)d_in[14]; const float* bhg = (const float*)d_in[15];
    const float* who = (const float*)d_in[16]; const float* bho = (const float*)d_in[17];
    const float* wci = (const float*)d_in[18];
    const float* wcf = (const float*)d_in[19];
    const float* wco = (const float*)d_in[20];

    ushort* Wt  = (ushort*)d_ws;                               // 1024*3456 bf16 = 6.75 MiB
    float* btot = (float*)((char*)d_ws + (size_t)1024 * 3456 * 2);

    prep_wt<<<dim3(1536), 256, 0, stream>>>(wii, wif, wig, wio, whi, whf, whg, who, Wt);
    prep_bias<<<dim3(4), 256, 0, stream>>>(bii, bif, big, bio, bhi, bhf, bhg, bho, btot);
    convlstm_main<<<dim3(4, 512), 256, 0, stream>>>(x, hidden, Wt, btot, wci, wcf, wco,
                                                    (float*)d_out);
}